// Round 7
// baseline (156.250 us; speedup 1.0000x reference)
//
#include <hip/hip_runtime.h>
#include <cmath>

#define BB 32
#define SS 256
#define HH 768

typedef __attribute__((ext_vector_type(8))) short bfrag8;
typedef __attribute__((ext_vector_type(4))) float accf4;

__device__ __forceinline__ unsigned short f2bf(float x) {   // RTNE fp32->bf16
    unsigned int b = __float_as_uint(x);
    return (unsigned short)((b + 0x7FFFu + ((b >> 16) & 1u)) >> 16);
}

__device__ __forceinline__ float bf2f(unsigned short u) {
    return __uint_as_float(((unsigned int)u) << 16);
}

__device__ __forceinline__ void gload16(const void* g, void* l) {
    __builtin_amdgcn_global_load_lds((const __attribute__((address_space(1))) void*)g,
                                     (__attribute__((address_space(3))) void*)l, 16, 0, 0);
}

// Both planes [b][kc][srow][32] bf16, SWIZZLED: fragment (row,f) stored at slot
// f ^ ((row>>1)&3). Staged to LDS as a linear image via global_load_lds; mfma
// ds_read_b128 with perm8 swizzle tiles all 8 bank-groups (0 conflicts, R0/R6).

// ---- normcvt: norms + normalized-bf16 swizzled pack (R6 verbatim; passed) ----
__global__ __launch_bounds__(256)
void normcvt_kernel(const float* __restrict__ Q, const float* __restrict__ K,
                    unsigned short* __restrict__ qws, unsigned short* __restrict__ kws) {
    const int wave = threadIdx.x >> 6, lane = threadIdx.x & 63;
    const bool isQ = blockIdx.x < 2048;          // rows 0..8191 = Q, else K
    const int rr = (blockIdx.x * 4 + wave) & 8191;
    const float4* src4 = isQ ? (const float4*)(Q + (size_t)rr * HH)
                             : (const float4*)(K + (size_t)rr * HH);
    float4 vv[3]; float s = 0.f;
#pragma unroll
    for (int c = 0; c < 3; ++c) {
        vv[c] = src4[lane + 64 * c];
        s += vv[c].x * vv[c].x + vv[c].y * vv[c].y + vv[c].z * vv[c].z + vv[c].w * vv[c].w;
    }
#pragma unroll
    for (int off = 1; off < 64; off <<= 1) s += __shfl_xor(s, off);
    float inv = 1.f / fmaxf(sqrtf(s), 1e-12f);

    const int b = rr >> 8, srow = rr & 255;
    unsigned short* dst = isQ ? qws : kws;
    const int e = (lane & 7) * 4;                 // element index of this lane's 4 shorts
    const int fp8 = (((e >> 3) ^ ((srow >> 1) & 3)) << 3) + (e & 7);   // swizzled slot
#pragma unroll
    for (int c = 0; c < 3; ++c) {
        int kc = (lane >> 3) + 8 * c;
        ushort4 o;
        o.x = f2bf(vv[c].x * inv); o.y = f2bf(vv[c].y * inv);
        o.z = f2bf(vv[c].z * inv); o.w = f2bf(vv[c].w * inv);
        *(ushort4*)(dst + (((size_t)b * 24 + kc) * 256 + srow) * 32 + fp8) = o;
    }
}

// ---- ksum: masked K column sums -> ksumB bf16 (R6 verbatim; passed) ----
__global__ __launch_bounds__(256)
void ksum_kernel(const unsigned short* __restrict__ kws, const float* __restrict__ kmask,
                 unsigned short* __restrict__ ksumB) {
    __shared__ float red[4][8][4];   // [wave][ec][4 elems]
    const int j = blockIdx.x / 24, kc = blockIdx.x - j * 24;
    const int lane = threadIdx.x & 63, wv = threadIdx.x >> 6;
    const int tg = threadIdx.x >> 3;              // 0..31
    const int ec = threadIdx.x & 7;               // elem chunk
    const unsigned short* base = kws + ((size_t)(j * 24 + kc)) * 8192;
    const float* km = kmask + j * SS;
    const int f = ec >> 1, off4 = (ec & 1) * 4;   // frag id, offset within frag
    float s0 = 0.f, s1 = 0.f, s2 = 0.f, s3 = 0.f;
    for (int t = tg; t < 256; t += 32) {
        if (km[t] > 0.f) {
            int pos = ((f ^ ((t >> 1) & 3)) << 3) + off4;    // un-swizzle
            ushort4 v = *(const ushort4*)(base + t * 32 + pos);
            s0 += bf2f(v.x); s1 += bf2f(v.y); s2 += bf2f(v.z); s3 += bf2f(v.w);
        }
    }
#pragma unroll
    for (int off = 8; off < 64; off <<= 1) {
        s0 += __shfl_xor(s0, off); s1 += __shfl_xor(s1, off);
        s2 += __shfl_xor(s2, off); s3 += __shfl_xor(s3, off);
    }
    if ((lane >> 3) == 0) {
        red[wv][ec][0] = s0; red[wv][ec][1] = s1; red[wv][ec][2] = s2; red[wv][ec][3] = s3;
    }
    __syncthreads();
    if (threadIdx.x < 32) {
        int e2 = threadIdx.x;
        float tot = red[0][e2 >> 2][e2 & 3] + red[1][e2 >> 2][e2 & 3]
                  + red[2][e2 >> 2][e2 & 3] + red[3][e2 >> 2][e2 & 3];
        ksumB[(size_t)(j * 24 + kc) * 32 + e2] = f2bf(tot);
    }
}

// ---- main: 2x2 (i,j) tile per block. 512 threads = 8 waves; waves 0-3 own
// plane i0, waves 4-7 own plane i0+1; each wave computes its 64 s-rows against
// BOTH j planes. Staging: 2 Q + 2 K planes (64KB), each wave stages a half-plane
// (8 x gload16). Same single-buffer 2-barrier-per-kc structure as R0 (4 schedule
// experiments lost to it). Total staged bytes: 806 -> 403 MB.
__global__ __launch_bounds__(512, 2)
void mfma_kernel(const unsigned short* __restrict__ qws, const unsigned short* __restrict__ kws,
                 const float* __restrict__ qmask, const float* __restrict__ kmask,
                 const float* __restrict__ araw_p, const float* __restrict__ lscale_p,
                 const unsigned short* __restrict__ ksumB, float* __restrict__ out) {
    __shared__ __align__(16) short lq[2][8192];   // 2 Q planes (swizzled image)
    __shared__ __align__(16) short lk[2][8192];   // 2 K planes
    __shared__ __align__(16) short lKsum[2][768]; // ksumB for j0, j0+1
    __shared__ float sKm[2][256];
    __shared__ float wtab[13];
    __shared__ float sRed[8][2];
    __shared__ float sPart[8][2];
    __shared__ float sKcnt[2], sQden[2];

    const int tid = threadIdx.x;                  // 0..511
    const int lane = tid & 63, w = tid >> 6;      // 8 waves
    const int quad = lane >> 4, col = lane & 15;
    const int li = w >> 2, wq = w & 3;            // i-half, quarter within plane

    // XCD-aware 2D swizzle: each XCD gets a 4ip x 8jp sub-grid -> per-kc working
    // set (24 x 16KB slices) stays resident in its 4MB L2.
    const int xcd = (int)blockIdx.x & 7, bidx = (int)blockIdx.x >> 3;
    const int ip = (xcd >> 1) * 4 + (bidx >> 3);  // 0..15
    const int jp = (xcd & 1) * 8 + (bidx & 7);    // 0..15
    const int i0 = ip * 2, j0 = jp * 2;

    const float alpha = log1pf(__expf(araw_p[0]));
    const float scale = __expf(lscale_p[0]);

    // ---- phase A: masks, denominators, Ksum fragments ----
    const int half = tid >> 8, hidx = tid & 255;  // half == li for this wave
    float aq = qmask[(i0 + half) * SS + hidx];
    float km = kmask[(j0 + half) * SS + hidx];
    sKm[half][hidx] = km;
    float c = (km > 0.f) ? 1.f : 0.f;
#pragma unroll
    for (int off = 1; off < 64; off <<= 1) { aq += __shfl_xor(aq, off); c += __shfl_xor(c, off); }
    if (lane == 0) { sRed[w][0] = aq; sRed[w][1] = c; }
    if (tid < 13) wtab[tid] = __expf(-alpha * (float)tid);
    if (tid < 384) {
        const int jj = (tid >= 192) ? 1 : 0, e = tid - jj * 192;
        ((ushort4*)&lKsum[jj][0])[e] = ((const ushort4*)(ksumB + (size_t)(j0 + jj) * HH))[e];
    }
    __syncthreads();
    if (tid == 0) {
        sQden[0] = fmaxf(sRed[0][0] + sRed[1][0] + sRed[2][0] + sRed[3][0], 1.f);
        sQden[1] = fmaxf(sRed[4][0] + sRed[5][0] + sRed[6][0] + sRed[7][0], 1.f);
        sKcnt[0] = sRed[0][1] + sRed[1][1] + sRed[2][1] + sRed[3][1];
        sKcnt[1] = sRed[4][1] + sRed[5][1] + sRed[6][1] + sRed[7][1];
    }

    accf4 acc[2][4][3];    // [lj][sbl][dtb]
    accf4 accB[2][4];      // [lj][sbl]
#pragma unroll
    for (int lj = 0; lj < 2; ++lj) {
#pragma unroll
        for (int a = 0; a < 4; ++a) {
            accB[lj][a] = (accf4)0.f;
#pragma unroll
            for (int b = 0; b < 3; ++b) acc[lj][a][b] = (accf4)0.f;
        }
    }

    // staging assignment: wave w stages half of plane p = w>>1
    //   p: 0 -> lq[0] (i0), 1 -> lq[1] (i0+1), 2 -> lk[0] (j0), 3 -> lk[1] (j0+1)
    const unsigned short* psrc = (w < 4)
        ? qws + (size_t)(i0 + ((w >> 1) & 1)) * 24 * 8192
        : kws + (size_t)(j0 + ((w >> 1) & 1)) * 24 * 8192;
    unsigned short* pdst = (unsigned short*)((w < 4) ? lq[(w >> 1) & 1] : lk[(w >> 1) & 1])
                           + (w & 1) * 4096;                 // wave-uniform LDS base
    const unsigned short* ssrc = psrc + (w & 1) * 4096 + lane * 8;

    const int perm8 = ((quad ^ ((col >> 1) & 3)) << 3);      // swizzled fragment slot

    // ---- K loop: 24 chunks of 32 (R0's barrier structure) ----
    for (int kc = 0; kc < 24; ++kc) {
        __syncthreads();
        {
            const unsigned short* s = ssrc + (size_t)kc * 8192;
#pragma unroll
            for (int n = 0; n < 8; ++n)
                gload16(s + n * 512, pdst + n * 512);
        }
        __syncthreads();

        bfrag8 af[4];
#pragma unroll
        for (int sbl = 0; sbl < 4; ++sbl)
            af[sbl] = *(const bfrag8*)(&lq[li][(size_t)((wq * 4 + sbl) * 16 + col) * 32 + perm8]);
#pragma unroll
        for (int lj = 0; lj < 2; ++lj) {
            const bfrag8 kfrag = *(const bfrag8*)(&lKsum[lj][kc * 32 + quad * 8]);
            bfrag8 bfr[6];
#pragma unroll
            for (int u = 0; u < 6; ++u) {
                int tb = 4 * wq - 1 + u;
                if (tb >= 0 && tb <= 15)
                    bfr[u] = *(const bfrag8*)(&lk[lj][(size_t)(tb * 16 + col) * 32 + perm8]);
            }
#pragma unroll
            for (int sbl = 0; sbl < 4; ++sbl) {
                accB[lj][sbl] = __builtin_amdgcn_mfma_f32_16x16x32_bf16(
                    af[sbl], kfrag, accB[lj][sbl], 0, 0, 0);
#pragma unroll
                for (int dtb = 0; dtb < 3; ++dtb) {
                    int tb = 4 * wq + sbl - 1 + dtb;
                    if (tb >= 0 && tb <= 15)
                        acc[lj][sbl][dtb] = __builtin_amdgcn_mfma_f32_16x16x32_bf16(
                            af[sbl], bfr[sbl + dtb], acc[lj][sbl][dtb], 0, 0, 0);
                }
            }
        }
    }

    // ---- epilogue: C/D layout col=lane&15 (t), row=quad*4+reg (s) ----
    __syncthreads();
    float part[2] = {0.f, 0.f};
#pragma unroll
    for (int lj = 0; lj < 2; ++lj) {
        const float kcnt = sKcnt[lj];
#pragma unroll
        for (int sbl = 0; sbl < 4; ++sbl) {
            const int sbase = (wq * 4 + sbl) * 16 + quad * 4;
            float ns[4] = {0.f, 0.f, 0.f, 0.f}, ds[4] = {0.f, 0.f, 0.f, 0.f};
#pragma unroll
            for (int dtb = 0; dtb < 3; ++dtb) {
                int tb = wq * 4 + sbl - 1 + dtb;
                if (tb < 0 || tb > 15) continue;
                int t = tb * 16 + col;
                float kmv = sKm[lj][t];
#pragma unroll
                for (int reg = 0; reg < 4; ++reg) {
                    int st = sbase + reg;
                    int d = t - st;
                    bool ok = (d >= -11) && (d <= 12) && (kmv > 0.f);
                    int idx = d < 0 ? -d : d;
                    idx = ok ? idx : 0;
                    float raw = acc[lj][sbl][dtb][reg];
                    float e = ok ? expm1f(scale * raw * wtab[idx]) : 0.f;
                    ns[reg] = fmaf(e, raw, ns[reg]);
                    ds[reg] += e;
                }
            }
#pragma unroll
            for (int off = 1; off < 16; off <<= 1) {
#pragma unroll
                for (int reg = 0; reg < 4; ++reg) {
                    ns[reg] += __shfl_xor(ns[reg], off);
                    ds[reg] += __shfl_xor(ds[reg], off);
                }
            }
            if (col == 0) {
#pragma unroll
                for (int reg = 0; reg < 4; ++reg) {
                    int st = sbase + reg;
                    float qm = qmask[(i0 + li) * SS + st];
                    float bse = accB[lj][sbl][reg];
                    float dtot = ds[reg] + kcnt;
                    float v = (qm > 0.f && kcnt > 0.f) ? qm * (ns[reg] + bse) / dtot : 0.f;
                    part[lj] += v;
                }
            }
        }
    }
#pragma unroll
    for (int lj = 0; lj < 2; ++lj) {
        part[lj] += __shfl_xor(part[lj], 16);
        part[lj] += __shfl_xor(part[lj], 32);
    }
    if (lane == 0) { sPart[w][0] = part[0]; sPart[w][1] = part[1]; }
    __syncthreads();
    if (tid < 4) {
        const int tli = tid >> 1, tlj = tid & 1;
        float s = sPart[tli * 4 + 0][tlj] + sPart[tli * 4 + 1][tlj]
                + sPart[tli * 4 + 2][tlj] + sPart[tli * 4 + 3][tlj];
        out[(i0 + tli) * BB + (j0 + tlj)] = s / sQden[tli];
    }
}

// ============ launcher ============

extern "C" void kernel_launch(void* const* d_in, const int* in_sizes, int n_in,
                              void* d_out, int out_size, void* d_ws, size_t ws_size,
                              hipStream_t stream) {
    const float* Q      = (const float*)d_in[0];
    const float* K      = (const float*)d_in[1];
    const float* qmask  = (const float*)d_in[2];
    const float* kmask  = (const float*)d_in[3];
    const float* araw   = (const float*)d_in[4];
    const float* lscale = (const float*)d_in[5];
    float* outp = (float*)d_out;

    unsigned short* ksumB = (unsigned short*)d_ws;            // 24576 us
    unsigned short* qws = ksumB + 24576;                      // 6291456 us
    unsigned short* kws = qws + 6291456;                      // 6291456 us

    normcvt_kernel<<<4096, 256, 0, stream>>>(Q, K, qws, kws);
    ksum_kernel<<<768, 256, 0, stream>>>(kws, kmask, ksumB);
    mfma_kernel<<<256, 512, 0, stream>>>(qws, kws, qmask, kmask, araw, lscale, ksumB, outp);
}

// Round 8
// 144.370 us; speedup vs baseline: 1.0823x; 1.0823x over previous
//
#include <hip/hip_runtime.h>
#include <cmath>

#define BB 32
#define SS 256
#define HH 768

typedef __attribute__((ext_vector_type(8))) short bfrag8;
typedef __attribute__((ext_vector_type(4))) float accf4;

__device__ __forceinline__ unsigned short f2bf(float x) {   // RTNE fp32->bf16
    unsigned int b = __float_as_uint(x);
    return (unsigned short)((b + 0x7FFFu + ((b >> 16) & 1u)) >> 16);
}

__device__ __forceinline__ float bf2f(unsigned short u) {
    return __uint_as_float(((unsigned int)u) << 16);
}

__device__ __forceinline__ void gload16(const void* g, void* l) {
    __builtin_amdgcn_global_load_lds((const __attribute__((address_space(1))) void*)g,
                                     (__attribute__((address_space(3))) void*)l, 16, 0, 0);
}

// Both planes [b][kc][srow][32] bf16, SWIZZLED: fragment (row,f) stored at slot
// f ^ ((row>>1)&3). Staged to LDS as a linear image via global_load_lds; mfma
// ds_read_b128 with perm8 swizzle tiles all 8 bank-groups (0 conflicts, R0/R6).

// ---- normcvt: norms + normalized-bf16 swizzled pack (R6 verbatim; passed) ----
__global__ __launch_bounds__(256)
void normcvt_kernel(const float* __restrict__ Q, const float* __restrict__ K,
                    unsigned short* __restrict__ qws, unsigned short* __restrict__ kws) {
    const int wave = threadIdx.x >> 6, lane = threadIdx.x & 63;
    const bool isQ = blockIdx.x < 2048;          // rows 0..8191 = Q, else K
    const int rr = (blockIdx.x * 4 + wave) & 8191;
    const float4* src4 = isQ ? (const float4*)(Q + (size_t)rr * HH)
                             : (const float4*)(K + (size_t)rr * HH);
    float4 vv[3]; float s = 0.f;
#pragma unroll
    for (int c = 0; c < 3; ++c) {
        vv[c] = src4[lane + 64 * c];
        s += vv[c].x * vv[c].x + vv[c].y * vv[c].y + vv[c].z * vv[c].z + vv[c].w * vv[c].w;
    }
#pragma unroll
    for (int off = 1; off < 64; off <<= 1) s += __shfl_xor(s, off);
    float inv = 1.f / fmaxf(sqrtf(s), 1e-12f);

    const int b = rr >> 8, srow = rr & 255;
    unsigned short* dst = isQ ? qws : kws;
    const int e = (lane & 7) * 4;                 // element index of this lane's 4 shorts
    const int fp8 = (((e >> 3) ^ ((srow >> 1) & 3)) << 3) + (e & 7);   // swizzled slot
#pragma unroll
    for (int c = 0; c < 3; ++c) {
        int kc = (lane >> 3) + 8 * c;
        ushort4 o;
        o.x = f2bf(vv[c].x * inv); o.y = f2bf(vv[c].y * inv);
        o.z = f2bf(vv[c].z * inv); o.w = f2bf(vv[c].w * inv);
        *(ushort4*)(dst + (((size_t)b * 24 + kc) * 256 + srow) * 32 + fp8) = o;
    }
}

// ---- ksum: masked K column sums -> ksumB bf16 (R6 verbatim; passed) ----
__global__ __launch_bounds__(256)
void ksum_kernel(const unsigned short* __restrict__ kws, const float* __restrict__ kmask,
                 unsigned short* __restrict__ ksumB) {
    __shared__ float red[4][8][4];   // [wave][ec][4 elems]
    const int j = blockIdx.x / 24, kc = blockIdx.x - j * 24;
    const int lane = threadIdx.x & 63, wv = threadIdx.x >> 6;
    const int tg = threadIdx.x >> 3;              // 0..31
    const int ec = threadIdx.x & 7;               // elem chunk
    const unsigned short* base = kws + ((size_t)(j * 24 + kc)) * 8192;
    const float* km = kmask + j * SS;
    const int f = ec >> 1, off4 = (ec & 1) * 4;   // frag id, offset within frag
    float s0 = 0.f, s1 = 0.f, s2 = 0.f, s3 = 0.f;
    for (int t = tg; t < 256; t += 32) {
        if (km[t] > 0.f) {
            int pos = ((f ^ ((t >> 1) & 3)) << 3) + off4;    // un-swizzle
            ushort4 v = *(const ushort4*)(base + t * 32 + pos);
            s0 += bf2f(v.x); s1 += bf2f(v.y); s2 += bf2f(v.z); s3 += bf2f(v.w);
        }
    }
#pragma unroll
    for (int off = 8; off < 64; off <<= 1) {
        s0 += __shfl_xor(s0, off); s1 += __shfl_xor(s1, off);
        s2 += __shfl_xor(s2, off); s3 += __shfl_xor(s3, off);
    }
    if ((lane >> 3) == 0) {
        red[wv][ec][0] = s0; red[wv][ec][1] = s1; red[wv][ec][2] = s2; red[wv][ec][3] = s3;
    }
    __syncthreads();
    if (threadIdx.x < 32) {
        int e2 = threadIdx.x;
        float tot = red[0][e2 >> 2][e2 & 3] + red[1][e2 >> 2][e2 & 3]
                  + red[2][e2 >> 2][e2 & 3] + red[3][e2 >> 2][e2 & 3];
        ksumB[(size_t)(j * 24 + kc) * 32 + e2] = f2bf(tot);
    }
}

// ---- main: 1x2 (i, j-pair) tile per block. 512 threads = 8 waves; wave w owns
// s-blocks {2w, 2w+1} of the single i plane, computed against BOTH j planes.
// Staging per kc: 1 Q + 2 K planes (48 KB): wave loads n={0,1}->lq, {2,3}->lk[0],
// {4,5}->lk[1] (6 gload16, all wave-uniform LDS bases). Grid 512 = 2 blocks/CU,
// 16 waves/CU (same as R0) -> drain/compute overlap preserved; staged bytes
// 806 -> 590 MB. Per-wave shape (16 MFMA, 64 acc floats) identical to R0.
__global__ __launch_bounds__(512, 4)
void mfma_kernel(const unsigned short* __restrict__ qws, const unsigned short* __restrict__ kws,
                 const float* __restrict__ qmask, const float* __restrict__ kmask,
                 const float* __restrict__ araw_p, const float* __restrict__ lscale_p,
                 const unsigned short* __restrict__ ksumB, float* __restrict__ out) {
    __shared__ __align__(16) short lq[8192];      // Q plane (swizzled image)
    __shared__ __align__(16) short lk[2][8192];   // 2 K planes
    __shared__ __align__(16) short lKsum[2][768]; // ksumB for j0, j0+1
    __shared__ float sKm[2][256];
    __shared__ float wtab[13];
    __shared__ float sRed[8][2];
    __shared__ float sPart[8][2];
    __shared__ float sKcnt[2], sQden;

    const int tid = threadIdx.x;                  // 0..511
    const int lane = tid & 63, w = tid >> 6;      // 8 waves
    const int quad = lane >> 4, col = lane & 15;

    const int i = (int)blockIdx.x >> 4;           // 0..31
    const int jp = (int)blockIdx.x & 15;          // 0..15
    const int j0 = jp * 2;

    const float alpha = log1pf(__expf(araw_p[0]));
    const float scale = __expf(lscale_p[0]);

    // ---- phase A: masks, denominators, Ksum fragments ----
    const int half = tid >> 8, hidx = tid & 255;  // half == w>>2
    float aq = qmask[i * SS + hidx];              // both halves load same (harmless)
    float km = kmask[(j0 + half) * SS + hidx];
    sKm[half][hidx] = km;
    float c = (km > 0.f) ? 1.f : 0.f;
#pragma unroll
    for (int off = 1; off < 64; off <<= 1) { aq += __shfl_xor(aq, off); c += __shfl_xor(c, off); }
    if (lane == 0) { sRed[w][0] = aq; sRed[w][1] = c; }
    if (tid < 13) wtab[tid] = __expf(-alpha * (float)tid);
    if (tid < 384) {
        const int jj = (tid >= 192) ? 1 : 0, e = tid - jj * 192;
        ((ushort4*)&lKsum[jj][0])[e] = ((const ushort4*)(ksumB + (size_t)(j0 + jj) * HH))[e];
    }
    __syncthreads();
    if (tid == 0) {
        sQden = fmaxf(sRed[0][0] + sRed[1][0] + sRed[2][0] + sRed[3][0], 1.f);
        sKcnt[0] = sRed[0][1] + sRed[1][1] + sRed[2][1] + sRed[3][1];
        sKcnt[1] = sRed[4][1] + sRed[5][1] + sRed[6][1] + sRed[7][1];
    }

    accf4 acc[2][2][3];    // [lj][sbl][dtb]  — 48 floats
    accf4 accB[2][2];      // [lj][sbl]       — 16 floats
#pragma unroll
    for (int lj = 0; lj < 2; ++lj) {
#pragma unroll
        for (int a = 0; a < 2; ++a) {
            accB[lj][a] = (accf4)0.f;
#pragma unroll
            for (int b = 0; b < 3; ++b) acc[lj][a][b] = (accf4)0.f;
        }
    }

    // staging sources (swizzled linear images)
    const unsigned short* qsrc  = qws + (size_t)i * 24 * 8192        + (size_t)w * 1024 + lane * 8;
    const unsigned short* ksrc0 = kws + (size_t)j0 * 24 * 8192       + (size_t)w * 1024 + lane * 8;
    const unsigned short* ksrc1 = kws + (size_t)(j0 + 1) * 24 * 8192 + (size_t)w * 1024 + lane * 8;
    unsigned short* lqd  = (unsigned short*)lq    + w * 1024;   // wave-uniform bases
    unsigned short* lk0d = (unsigned short*)lk[0] + w * 1024;
    unsigned short* lk1d = (unsigned short*)lk[1] + w * 1024;

    const int perm8 = ((quad ^ ((col >> 1) & 3)) << 3);      // swizzled fragment slot

    // ---- K loop: 24 chunks of 32 (R0's 2-barrier structure) ----
    for (int kc = 0; kc < 24; ++kc) {
        __syncthreads();
        {
            const size_t o = (size_t)kc * 8192;
            gload16(qsrc  + o,       lqd);
            gload16(qsrc  + o + 512, lqd  + 512);
            gload16(ksrc0 + o,       lk0d);
            gload16(ksrc0 + o + 512, lk0d + 512);
            gload16(ksrc1 + o,       lk1d);
            gload16(ksrc1 + o + 512, lk1d + 512);
        }
        __syncthreads();

        bfrag8 af[2];
#pragma unroll
        for (int sbl = 0; sbl < 2; ++sbl)
            af[sbl] = *(const bfrag8*)(&lq[(size_t)((2 * w + sbl) * 16 + col) * 32 + perm8]);
#pragma unroll
        for (int lj = 0; lj < 2; ++lj) {
            const bfrag8 kfrag = *(const bfrag8*)(&lKsum[lj][kc * 32 + quad * 8]);
            bfrag8 bfr[4];
#pragma unroll
            for (int u = 0; u < 4; ++u) {
                int tb = 2 * w - 1 + u;
                if (tb >= 0 && tb <= 15)
                    bfr[u] = *(const bfrag8*)(&lk[lj][(size_t)(tb * 16 + col) * 32 + perm8]);
            }
#pragma unroll
            for (int sbl = 0; sbl < 2; ++sbl) {
                accB[lj][sbl] = __builtin_amdgcn_mfma_f32_16x16x32_bf16(
                    af[sbl], kfrag, accB[lj][sbl], 0, 0, 0);
#pragma unroll
                for (int dtb = 0; dtb < 3; ++dtb) {
                    int tb = 2 * w + sbl - 1 + dtb;
                    if (tb >= 0 && tb <= 15)
                        acc[lj][sbl][dtb] = __builtin_amdgcn_mfma_f32_16x16x32_bf16(
                            af[sbl], bfr[sbl + dtb], acc[lj][sbl][dtb], 0, 0, 0);
                }
            }
        }
    }

    // ---- epilogue: C/D layout col=lane&15 (t), row=quad*4+reg (s) ----
    __syncthreads();
    float part[2] = {0.f, 0.f};
#pragma unroll
    for (int lj = 0; lj < 2; ++lj) {
        const float kcnt = sKcnt[lj];
#pragma unroll
        for (int sbl = 0; sbl < 2; ++sbl) {
            const int sbase = (2 * w + sbl) * 16 + quad * 4;
            float ns[4] = {0.f, 0.f, 0.f, 0.f}, ds[4] = {0.f, 0.f, 0.f, 0.f};
#pragma unroll
            for (int dtb = 0; dtb < 3; ++dtb) {
                int tb = 2 * w + sbl - 1 + dtb;
                if (tb < 0 || tb > 15) continue;
                int t = tb * 16 + col;
                float kmv = sKm[lj][t];
#pragma unroll
                for (int reg = 0; reg < 4; ++reg) {
                    int st = sbase + reg;
                    int d = t - st;
                    bool ok = (d >= -11) && (d <= 12) && (kmv > 0.f);
                    int idx = d < 0 ? -d : d;
                    idx = ok ? idx : 0;
                    float raw = acc[lj][sbl][dtb][reg];
                    float e = ok ? expm1f(scale * raw * wtab[idx]) : 0.f;
                    ns[reg] = fmaf(e, raw, ns[reg]);
                    ds[reg] += e;
                }
            }
#pragma unroll
            for (int off = 1; off < 16; off <<= 1) {
#pragma unroll
                for (int reg = 0; reg < 4; ++reg) {
                    ns[reg] += __shfl_xor(ns[reg], off);
                    ds[reg] += __shfl_xor(ds[reg], off);
                }
            }
            if (col == 0) {
#pragma unroll
                for (int reg = 0; reg < 4; ++reg) {
                    int st = sbase + reg;
                    float qm = qmask[i * SS + st];
                    float bse = accB[lj][sbl][reg];
                    float dtot = ds[reg] + kcnt;
                    float v = (qm > 0.f && kcnt > 0.f) ? qm * (ns[reg] + bse) / dtot : 0.f;
                    part[lj] += v;
                }
            }
        }
    }
#pragma unroll
    for (int lj = 0; lj < 2; ++lj) {
        part[lj] += __shfl_xor(part[lj], 16);
        part[lj] += __shfl_xor(part[lj], 32);
    }
    if (lane == 0) { sPart[w][0] = part[0]; sPart[w][1] = part[1]; }
    __syncthreads();
    if (tid < 2) {
        float s = 0.f;
#pragma unroll
        for (int ww = 0; ww < 8; ++ww) s += sPart[ww][tid];
        out[i * BB + (j0 + tid)] = s / sQden;
    }
}

// ============ launcher ============

extern "C" void kernel_launch(void* const* d_in, const int* in_sizes, int n_in,
                              void* d_out, int out_size, void* d_ws, size_t ws_size,
                              hipStream_t stream) {
    const float* Q      = (const float*)d_in[0];
    const float* K      = (const float*)d_in[1];
    const float* qmask  = (const float*)d_in[2];
    const float* kmask  = (const float*)d_in[3];
    const float* araw   = (const float*)d_in[4];
    const float* lscale = (const float*)d_in[5];
    float* outp = (float*)d_out;

    unsigned short* ksumB = (unsigned short*)d_ws;            // 24576 us
    unsigned short* qws = ksumB + 24576;                      // 6291456 us
    unsigned short* kws = qws + 6291456;                      // 6291456 us

    normcvt_kernel<<<4096, 256, 0, stream>>>(Q, K, qws, kws);
    ksum_kernel<<<768, 256, 0, stream>>>(kws, kmask, ksumB);
    mfma_kernel<<<512, 512, 0, stream>>>(qws, kws, qmask, kmask, araw, lscale, ksumB, outp);
}